// Round 3
// baseline (2277.657 us; speedup 1.0000x reference)
//
#include <hip/hip_runtime.h>
#include <hip/hip_bf16.h>

// Problem constants
#define S_LEN 2048
#define NHEAD 32     // heads per batch
#define HDIM  128
#define HSZ   4096
#define NH_TOT 64    // B * NH
#define INV_NORM 0.08838834764831845f       // 1/sqrt(128)
#define NEG_MIN  -3.4028234663852886e38f    // finfo(float32).min

typedef __attribute__((ext_vector_type(8))) __bf16 bf16x8;
typedef __attribute__((ext_vector_type(4))) float  floatx4;

__device__ __forceinline__ float bf2f(__hip_bfloat16 x) { return __bfloat162float(x); }

// async 16B global->LDS. lds ptr must be wave-uniform; HW scatters lane i to base + i*16.
__device__ __forceinline__ void gload16(const void* g, void* l) {
  __builtin_amdgcn_global_load_lds(
      (__attribute__((address_space(1))) void*)g,
      (__attribute__((address_space(3))) void*)l, 16, 0, 0);
}

// ---------------------------------------------------------------------------
// f32 -> bf16 conversion (vectorized, 4 elems/thread)
// ---------------------------------------------------------------------------
__global__ __launch_bounds__(256) void cvt_f32_bf16(
    const float* __restrict__ in, __hip_bfloat16* __restrict__ out, size_t n)
{
  const size_t i = ((size_t)blockIdx.x * 256 + threadIdx.x) * 4;
  if (i < n) {
    const float4 v = *(const float4*)(in + i);
    __hip_bfloat16 o0 = __float2bfloat16(v.x);
    __hip_bfloat16 o1 = __float2bfloat16(v.y);
    __hip_bfloat16 o2 = __float2bfloat16(v.z);
    __hip_bfloat16 o3 = __float2bfloat16(v.w);
    ushort4 pk;
    pk.x = *(unsigned short*)&o0; pk.y = *(unsigned short*)&o1;
    pk.z = *(unsigned short*)&o2; pk.w = *(unsigned short*)&o3;
    *(ushort4*)(out + i) = pk;
  }
}

// ---------------------------------------------------------------------------
// QKV GEMM: C[4096, 12288] = hidden[4096,4096] @ qkv_w[12288,4096]^T + qkv_b
// A, W pre-converted to bf16; bias is f32. Epilogue scatters to
// Qb[h][s][d], Kb[h][s][d], Vt[h][d][s] (bf16).
// ---------------------------------------------------------------------------
__global__ __launch_bounds__(256) void qkv_gemm(
    const __hip_bfloat16* __restrict__ A,     // [4096, 4096] bf16
    const __hip_bfloat16* __restrict__ W,     // [12288, 4096] bf16
    const float* __restrict__ bias,           // [12288] f32
    __hip_bfloat16* __restrict__ Qb,
    __hip_bfloat16* __restrict__ Kb,
    __hip_bfloat16* __restrict__ Vt)
{
  __shared__ __align__(16) __hip_bfloat16 As[128 * 32];
  __shared__ __align__(16) __hip_bfloat16 Bs[128 * 32];
  const int K  = 4096;
  const int m0 = blockIdx.y * 128;
  const int n0 = blockIdx.x * 128;
  const int t  = threadIdx.x;
  const int w  = t >> 6;
  const int l  = t & 63;
  const int wr = w >> 1, wc = w & 1;
  const int quad = l >> 4, ln = l & 15;

  floatx4 acc[4][4] = {};

  const int r1 = t >> 2,         c1 = (t & 3) * 8;
  const int r2 = (t >> 2) + 64,  c2 = (t & 3) * 8;
  char* AsB = (char*)As;
  char* BsB = (char*)Bs;
  const int wb1 = (w * 64) * 16;
  const int wb2 = (256 + w * 64) * 16;

  for (int k0 = 0; k0 < K; k0 += 32) {
    gload16(A + (size_t)(m0 + r1) * K + k0 + c1, AsB + wb1);
    gload16(W + (size_t)(n0 + r1) * K + k0 + c1, BsB + wb1);
    gload16(A + (size_t)(m0 + r2) * K + k0 + c2, AsB + wb2);
    gload16(W + (size_t)(n0 + r2) * K + k0 + c2, BsB + wb2);
    __syncthreads();
    bf16x8 af[4], bfr[4];
#pragma unroll
    for (int i = 0; i < 4; ++i)
      af[i] = *(const bf16x8*)(As + (wr * 64 + i * 16 + ln) * 32 + quad * 8);
#pragma unroll
    for (int j = 0; j < 4; ++j)
      bfr[j] = *(const bf16x8*)(Bs + (wc * 64 + j * 16 + ln) * 32 + quad * 8);
#pragma unroll
    for (int i = 0; i < 4; ++i)
#pragma unroll
      for (int j = 0; j < 4; ++j)
        acc[i][j] = __builtin_amdgcn_mfma_f32_16x16x32_bf16(af[i], bfr[j], acc[i][j], 0, 0, 0);
    __syncthreads();
  }

  // epilogue: n -> (nh, which, hd); m -> (b, s)
#pragma unroll
  for (int i = 0; i < 4; ++i) {
#pragma unroll
    for (int j = 0; j < 4; ++j) {
      const int n     = n0 + wc * 64 + j * 16 + ln;
      const int nh    = n / 384;
      const int which = (n >> 7) % 3;
      const int hd    = n & 127;
      const float bv  = bias[n];
#pragma unroll
      for (int r = 0; r < 4; ++r) {
        const int m  = m0 + wr * 64 + i * 16 + quad * 4 + r;
        const int bb = m >> 11;
        const int s  = m & 2047;
        const int head = bb * NHEAD + nh;
        const __hip_bfloat16 hv = __float2bfloat16(acc[i][j][r] + bv);
        if (which == 0)      Qb[((size_t)head * S_LEN + s) * HDIM + hd] = hv;
        else if (which == 1) Kb[((size_t)head * S_LEN + s) * HDIM + hd] = hv;
        else                 Vt[((size_t)head * HDIM + hd) * S_LEN + s] = hv;
      }
    }
  }
}

// ---------------------------------------------------------------------------
// Flash attention. One block per (head, 64 q-rows); 4 waves x 16 q-rows each.
// Output O overwrites the Q region IN PLACE (head-major [head][s][d]): each
// block reads only its own 64 Q rows (at kernel start) and writes only those
// same rows — no cross-block hazard.
// ---------------------------------------------------------------------------
__global__ __launch_bounds__(256) void flash_attn(
    __hip_bfloat16* __restrict__ Qb,           // [64, 2048, 128] in, O out
    const __hip_bfloat16* __restrict__ Kb,     // [64, 2048, 128]
    const __hip_bfloat16* __restrict__ Vt,     // [64, 128, 2048]
    const float* __restrict__ alibi,           // [64, 2048] f32
    const int* __restrict__ mask)              // [2, 2048, 2048] int
{
  __shared__ __align__(16) __hip_bfloat16 Psh[4][16 * 32];
  const int head = blockIdx.x >> 5;
  const int qblk = blockIdx.x & 31;
  const int t = threadIdx.x;
  const int w = t >> 6, l = t & 63;
  const int quad = l >> 4, ln = l & 15;
  const int b = head >> 5;
  const int q0 = qblk * 64 + w * 16;

  __hip_bfloat16* Qh = Qb + (size_t)head * S_LEN * HDIM;
  const __hip_bfloat16* Kh = Kb + (size_t)head * S_LEN * HDIM;
  const __hip_bfloat16* Vh = Vt + (size_t)head * HDIM * S_LEN;
  const float* al = alibi + (size_t)head * S_LEN;
  const int* mk = mask + (size_t)b * S_LEN * S_LEN;

  // Q fragments (A-operand): lane holds Q[q0+ln][ks*32 + quad*8 + j]
  bf16x8 qf[4];
#pragma unroll
  for (int ks = 0; ks < 4; ++ks)
    qf[ks] = *(const bf16x8*)(Qh + (size_t)(q0 + ln) * HDIM + ks * 32 + quad * 8);

  float m_run[4], l_run[4], sv[2][4], alp[4];
  floatx4 accO[8] = {};
#pragma unroll
  for (int r = 0; r < 4; ++r) { m_run[r] = -INFINITY; l_run[r] = 0.f; }

  __hip_bfloat16* Pw = Psh[w];

  for (int kj0 = 0; kj0 < S_LEN; kj0 += 32) {
    // scores: two 16-col tiles
#pragma unroll
    for (int tt = 0; tt < 2; ++tt) {
      const int kjb = kj0 + tt * 16;
      floatx4 accS = {};
#pragma unroll
      for (int ks = 0; ks < 4; ++ks) {
        bf16x8 kf = *(const bf16x8*)(Kh + (size_t)(kjb + ln) * HDIM + ks * 32 + quad * 8);
        accS = __builtin_amdgcn_mfma_f32_16x16x32_bf16(qf[ks], kf, accS, 0, 0, 0);
      }
      const int kj = kjb + ln;
      const float av = al[kj];
#pragma unroll
      for (int r = 0; r < 4; ++r) {
        const int qi = q0 + quad * 4 + r;
        float s = accS[r] * INV_NORM + av;
        if (mk[(size_t)qi * S_LEN + kj] != 0) s = NEG_MIN;
        sv[tt][r] = s;
      }
    }
    // online softmax (row spread over 16 lanes; xor 1,2,4,8 stays in quad group)
#pragma unroll
    for (int r = 0; r < 4; ++r) {
      float cm = fmaxf(sv[0][r], sv[1][r]);
      cm = fmaxf(cm, __shfl_xor(cm, 1, 64));
      cm = fmaxf(cm, __shfl_xor(cm, 2, 64));
      cm = fmaxf(cm, __shfl_xor(cm, 4, 64));
      cm = fmaxf(cm, __shfl_xor(cm, 8, 64));
      const float mn = fmaxf(m_run[r], cm);
      alp[r] = expf(m_run[r] - mn);
      m_run[r] = mn;
      const float p0 = expf(sv[0][r] - mn);
      const float p1 = expf(sv[1][r] - mn);
      sv[0][r] = p0; sv[1][r] = p1;
      float ps = p0 + p1;
      ps += __shfl_xor(ps, 1, 64);
      ps += __shfl_xor(ps, 2, 64);
      ps += __shfl_xor(ps, 4, 64);
      ps += __shfl_xor(ps, 8, 64);
      l_run[r] = l_run[r] * alp[r] + ps;
    }
#pragma unroll
    for (int dt = 0; dt < 8; ++dt)
#pragma unroll
      for (int r = 0; r < 4; ++r) accO[dt][r] *= alp[r];

    // P: C/D layout -> LDS -> A-operand layout
#pragma unroll
    for (int tt = 0; tt < 2; ++tt)
#pragma unroll
      for (int r = 0; r < 4; ++r)
        Pw[(quad * 4 + r) * 32 + tt * 16 + ln] = __float2bfloat16(sv[tt][r]);
    __syncthreads();
    const bf16x8 pf = *(const bf16x8*)(Pw + ln * 32 + quad * 8);

    // PV: accO[dt] covers d = dt*16 + ln
#pragma unroll
    for (int dt = 0; dt < 8; ++dt) {
      bf16x8 vf = *(const bf16x8*)(Vh + (size_t)(dt * 16 + ln) * S_LEN + kj0 + quad * 8);
      accO[dt] = __builtin_amdgcn_mfma_f32_16x16x32_bf16(pf, vf, accO[dt], 0, 0, 0);
    }
    __syncthreads();
  }

  // epilogue: O overwrites this block's own Q rows (head-major)
#pragma unroll
  for (int r = 0; r < 4; ++r) {
    const int qi = q0 + quad * 4 + r;
    const float invl = 1.0f / l_run[r];
#pragma unroll
    for (int dt = 0; dt < 8; ++dt)
      Qh[(size_t)qi * HDIM + dt * 16 + ln] = __float2bfloat16(accO[dt][r] * invl);
  }
}

// ---------------------------------------------------------------------------
// Dense GEMM: out[4096,4096] = ctx @ dense_w^T + dense_b + residual.
// ctx lives in the Q region, HEAD-MAJOR: element (b, s, nh, hd) at
// ((b*32+nh)*2048 + s)*128 + hd. k = nh*128+hd; 32-wide k-tiles never cross a
// head boundary, so 16B chunks stay contiguous. bias/residual/out are f32.
// ---------------------------------------------------------------------------
__global__ __launch_bounds__(256) void dense_gemm(
    const __hip_bfloat16* __restrict__ CtxQ,   // head-major ctx (Q region)
    const __hip_bfloat16* __restrict__ W,      // [4096, 4096] bf16
    const float* __restrict__ bias,            // [4096] f32
    const float* __restrict__ residual,        // [4096, 4096] f32
    float* __restrict__ out)                   // [4096, 4096] f32
{
  __shared__ __align__(16) __hip_bfloat16 As[128 * 32];
  __shared__ __align__(16) __hip_bfloat16 Bs[128 * 32];
  const int K  = 4096;
  const int m0 = blockIdx.y * 128;
  const int n0 = blockIdx.x * 128;
  const int t  = threadIdx.x;
  const int w  = t >> 6;
  const int l  = t & 63;
  const int wr = w >> 1, wc = w & 1;
  const int quad = l >> 4, ln = l & 15;

  floatx4 acc[4][4] = {};
  const int r1 = t >> 2,        c1 = (t & 3) * 8;
  const int r2 = (t >> 2) + 64, c2 = (t & 3) * 8;
  char* AsB = (char*)As;
  char* BsB = (char*)Bs;
  const int wb1 = (w * 64) * 16;
  const int wb2 = (256 + w * 64) * 16;

  // head-major A addressing (b uniform per block: m0 is 128-aligned, 2048%128==0)
  const int m1 = m0 + r1, b1 = m1 >> 11, s1 = m1 & 2047;
  const int m2 = m0 + r2, b2 = m2 >> 11, s2 = m2 & 2047;

  for (int k0 = 0; k0 < K; k0 += 32) {
    const int nh  = k0 >> 7;
    const int hd0 = k0 & 127;
    gload16(CtxQ + ((size_t)((b1 * NHEAD + nh) * S_LEN + s1)) * HDIM + hd0 + c1, AsB + wb1);
    gload16(W + (size_t)(n0 + r1) * K + k0 + c1, BsB + wb1);
    gload16(CtxQ + ((size_t)((b2 * NHEAD + nh) * S_LEN + s2)) * HDIM + hd0 + c2, AsB + wb2);
    gload16(W + (size_t)(n0 + r2) * K + k0 + c2, BsB + wb2);
    __syncthreads();
    bf16x8 af[4], bfr[4];
#pragma unroll
    for (int i = 0; i < 4; ++i)
      af[i] = *(const bf16x8*)(As + (wr * 64 + i * 16 + ln) * 32 + quad * 8);
#pragma unroll
    for (int j = 0; j < 4; ++j)
      bfr[j] = *(const bf16x8*)(Bs + (wc * 64 + j * 16 + ln) * 32 + quad * 8);
#pragma unroll
    for (int i = 0; i < 4; ++i)
#pragma unroll
      for (int j = 0; j < 4; ++j)
        acc[i][j] = __builtin_amdgcn_mfma_f32_16x16x32_bf16(af[i], bfr[j], acc[i][j], 0, 0, 0);
    __syncthreads();
  }

#pragma unroll
  for (int i = 0; i < 4; ++i) {
#pragma unroll
    for (int j = 0; j < 4; ++j) {
      const int n = n0 + wc * 64 + j * 16 + ln;
      const float bv = bias[n];
#pragma unroll
      for (int r = 0; r < 4; ++r) {
        const int m = m0 + wr * 64 + i * 16 + quad * 4 + r;
        out[(size_t)m * HSZ + n] =
            acc[i][j][r] + bv + residual[(size_t)m * HSZ + n];
      }
    }
  }
}

extern "C" void kernel_launch(void* const* d_in, const int* in_sizes, int n_in,
                              void* d_out, int out_size, void* d_ws, size_t ws_size,
                              hipStream_t stream) {
  const float* hidden   = (const float*)d_in[0];
  const float* residual = (const float*)d_in[1];
  const float* alibi    = (const float*)d_in[2];
  const int*   mask     = (const int*)d_in[3];
  const float* qkv_w    = (const float*)d_in[4];
  const float* qkv_b    = (const float*)d_in[5];
  const float* dense_w  = (const float*)d_in[6];
  const float* dense_b  = (const float*)d_in[7];
  float* out = (float*)d_out;   // reference output dtype is float32

  // workspace (bf16): Qb/Kb/Vt (33.5 MB each), Ah (33.5 MB, reused for dense_w),
  // Wq (100.7 MB). Peak ≈ 235 MB.
  const size_t per  = (size_t)NH_TOT * S_LEN * HDIM;  // 16,777,216 elems
  const size_t nWq  = (size_t)3 * HSZ * HSZ;          // 50,331,648 elems
  __hip_bfloat16* Qb = (__hip_bfloat16*)d_ws;
  __hip_bfloat16* Kb = Qb + per;
  __hip_bfloat16* Vt = Kb + per;
  __hip_bfloat16* Ah = Vt + per;        // hidden bf16, later reused for dense_w
  __hip_bfloat16* Wq = Ah + per;        // qkv_w bf16

  // convert f32 inputs to bf16
  cvt_f32_bf16<<<(int)(per / 4 / 256), 256, 0, stream>>>(hidden, Ah, per);
  cvt_f32_bf16<<<(int)(nWq / 4 / 256), 256, 0, stream>>>(qkv_w, Wq, nWq);

  qkv_gemm<<<dim3(96, 32), 256, 0, stream>>>(Ah, Wq, qkv_b, Qb, Kb, Vt);

  // Ah dead now — reuse for dense_w bf16
  cvt_f32_bf16<<<(int)(per / 4 / 256), 256, 0, stream>>>(dense_w, Ah, per);

  flash_attn<<<dim3(2048), 256, 0, stream>>>(Qb, Kb, Vt, alibi, mask);
  dense_gemm<<<dim3(32, 32), 256, 0, stream>>>(Qb, Ah, dense_b, residual, out);
}